// Round 8
// baseline (1389.362 us; speedup 1.0000x reference)
//
#include <hip/hip_runtime.h>
#include <math.h>

// ---------------------------------------------------------------------------
// GatedAttentionTransformer  (B=2, T=2048, D=1024, E=2048, S=128, L=4, V=32000)
// Round 8: gemm256 -> 256x128 tile, BK=32, 48KB LDS, <=128 VGPR,
//          2 blocks/CU (launch_bounds(512,4)). TLP overlaps epilogue/prologue
//          (R2-R7 showed schedule-retiming is flat at 1 block/CU).
// ---------------------------------------------------------------------------

#define Bz 2
#define Tt 2048
#define Dd 1024
#define Ee 2048
#define Ss 128
#define Ll 4
#define Vv 32000
#define BT (Bz * Tt)   // 4096

typedef __attribute__((ext_vector_type(8))) _Float16 f16x8;
typedef __attribute__((ext_vector_type(4))) _Float16 f16x4;
typedef __attribute__((ext_vector_type(4))) float    f32x4;

__device__ __forceinline__ void load_lds16(const void* g, void* l) {
  __builtin_amdgcn_global_load_lds(
      (const __attribute__((address_space(1))) void*)g,
      (__attribute__((address_space(3))) void*)l, 16, 0, 0);
}

#define FENCE asm volatile("" ::: "memory")
#define BARRIER do { FENCE; __builtin_amdgcn_s_barrier(); FENCE; } while (0)

enum { EPI_F32 = 0, EPI_SILU = 1, EPI_SCORES = 2, EPI_RESID = 3, EPI_GATED = 4 };

// bijective XCD swizzle (m204)
__device__ __forceinline__ int xcd_swz(int id, int nwg) {
  int q = nwg >> 3, r = nwg & 7;
  int x = id & 7, o = id >> 3;
  return (x < r ? x * (q + 1) : r * (q + 1) + (x - r) * q) + o;
}

// ===========================================================================
// 256x128 tile, BK=32, 8 waves (4M x 2N, wave tile 64x64), dbuf LDS 48KB,
// 2 blocks/CU. Granule-XOR LDS swizzle (4 granules/row, XOR row&3).
// Epilogue: multi-pass LDS-bounce -> full-line stores.
// Requires M%256==0, N%128==0, K%32==0, K>=64.
// ===========================================================================
template <int EPI>
__global__ void __launch_bounds__(512, 4) gemm256(
    const _Float16* __restrict__ A, long sA,
    const _Float16* __restrict__ Bt, long sB,
    void* __restrict__ Cp, long sC,
    int M, int N, int K, int lda, int ldb, int ldc) {
  const int bz = blockIdx.z;
  A += (size_t)bz * sA;
  Bt += (size_t)bz * sB;

  const int nbm = M >> 8;
  const int id = xcd_swz(blockIdx.x, gridDim.x);
  const int bm = id % nbm, bn = id / nbm;
  const int row0 = bm << 8, col0 = bn << 7;

  // 48 KiB: K-loop = A dbuf [2][8192] (32K) | B dbuf [2][4096] (16K);
  // epilogue reuses the first 32K as bounce buffer.
  __shared__ __align__(16) char smem[49152];
  _Float16* const Ab = (_Float16*)smem;              // [2][8192]
  _Float16* const Bb = (_Float16*)(smem + 32768);    // [2][4096]

  const int tid = threadIdx.x, lane = tid & 63, w = tid >> 6;
  const int mu = w >> 1, nu = w & 1;      // wave grid 4(M) x 2(N), tile 64x64
  const int fr = lane & 15, kg = lane >> 4;
  // staging: each load instr covers 128 rows x 32 cols (8 KB)
  const int srow = w * 16 + (lane >> 2);           // 0..127
  const int sg = (lane & 3) ^ ((lane >> 2) & 3);   // pre-swizzled src granule
  const _Float16* Asrc = A + (size_t)(row0 + srow) * lda + sg * 8;
  const _Float16* Bsrc = Bt + (size_t)(col0 + srow) * ldb + sg * 8;
  const int gA = ((kg ^ (fr & 3)) << 3);           // swizzled read granule

#define ST_A(BUF, KT, Q) load_lds16(Asrc + (size_t)(Q) * 128 * lda + (size_t)(KT) * 32, \
                                    (void*)&Ab[(BUF) * 8192 + (Q) * 4096 + w * 512])
#define ST_B(BUF, KT)    load_lds16(Bsrc + (size_t)(KT) * 32, \
                                    (void*)&Bb[(BUF) * 4096 + w * 512])

  f32x4 acc[4][4];
#pragma unroll
  for (int m = 0; m < 4; ++m)
#pragma unroll
    for (int n = 0; n < 4; ++n)
#pragma unroll
      for (int e = 0; e < 4; ++e) acc[m][n][e] = 0.f;

  f16x8 af[4], bf[4];

  const int NT = K >> 5;
  // prologue: stage tile 0 -> buf0
  ST_A(0, 0, 0); ST_A(0, 0, 1); ST_B(0, 0);
  asm volatile("s_waitcnt vmcnt(0)" ::: "memory");
  BARRIER;

  for (int t = 0; t < NT; ++t) {
    const int b = t & 1, nb = b ^ 1;
    const int kn = (t + 1 < NT) ? t + 1 : t;  // tail: re-stage (never read)
    // stage t+1 first (max lead), then read fragments of t
    ST_A(nb, kn, 0); ST_A(nb, kn, 1); ST_B(nb, kn);
#pragma unroll
    for (int m = 0; m < 4; ++m)
      af[m] = *(const f16x8*)&Ab[b * 8192 + (mu * 64 + m * 16 + fr) * 32 + gA];
#pragma unroll
    for (int n = 0; n < 4; ++n)
      bf[n] = *(const f16x8*)&Bb[b * 4096 + (nu * 64 + n * 16 + fr) * 32 + gA];
    asm volatile("s_waitcnt lgkmcnt(0)" ::: "memory");
    __builtin_amdgcn_sched_barrier(0);
    __builtin_amdgcn_s_setprio(1);
#pragma unroll
    for (int m = 0; m < 4; ++m)
#pragma unroll
      for (int n = 0; n < 4; ++n)
        acc[m][n] =
            __builtin_amdgcn_mfma_f32_16x16x32_f16(af[m], bf[n], acc[m][n], 0, 0, 0);
    __builtin_amdgcn_s_setprio(0);
    asm volatile("s_waitcnt vmcnt(0)" ::: "memory");  // t+1 resident
    BARRIER;
  }

  // ---- epilogue: LDS bounce -> coalesced full-line stores -------------------
  // acc (m,n,r): wave-local row = m*16 + kg*4 + r, col = nu*64 + n*16 + fr.
  if (EPI == EPI_F32) {
    float* Cb = (float*)Cp + (size_t)bz * sC;
#pragma unroll
    for (int p = 0; p < 4; ++p) {   // pass p: rows [p*64, p*64+64), 32 KB
      __syncthreads();
      if (mu == p) {
#pragma unroll
        for (int m = 0; m < 4; ++m)
#pragma unroll
          for (int n = 0; n < 4; ++n) {
            int col = nu * 64 + n * 16 + fr;
#pragma unroll
            for (int r = 0; r < 4; ++r) {
              int row = m * 16 + (kg << 2) + r;
              *(float*)(smem + (row << 9) + ((col << 2) ^ ((row & 7) << 4))) =
                  acc[m][n][r];
            }
          }
      }
      __syncthreads();
#pragma unroll
      for (int rr = 0; rr < 4; ++rr) {
        int row = rr * 16 + w * 2 + (lane >> 5);   // 0..63
        f32x4 d = *(const f32x4*)(smem + (row << 9) +
                                  (((lane & 31) << 4) ^ ((row & 7) << 4)));
        *(f32x4*)&Cb[(size_t)(row0 + p * 64 + row) * ldc + col0 +
                     ((lane & 31) << 2)] = d;
      }
    }
  } else {  // EPI_SILU: f16 out, 2 passes x 128 rows (32 KB each)
    _Float16* Ch = (_Float16*)Cp + (size_t)bz * sC;
#pragma unroll
    for (int p = 0; p < 2; ++p) {
      __syncthreads();
      if ((mu >> 1) == p) {
#pragma unroll
        for (int m = 0; m < 4; ++m)
#pragma unroll
          for (int n = 0; n < 4; ++n) {
            int col = nu * 64 + n * 16 + fr;
#pragma unroll
            for (int r = 0; r < 4; ++r) {
              int row = (mu & 1) * 64 + m * 16 + (kg << 2) + r;  // 0..127
              float v = acc[m][n][r];
              *(_Float16*)(smem + (row << 8) + ((col << 1) ^ ((row & 7) << 4))) =
                  (_Float16)(v / (1.f + expf(-v)));
            }
          }
      }
      __syncthreads();
#pragma unroll
      for (int rr = 0; rr < 4; ++rr) {
        int row = rr * 32 + w * 4 + (lane >> 4);   // 0..127
        f16x8 d = *(const f16x8*)(smem + (row << 8) +
                                  (((lane & 15) << 4) ^ ((row & 7) << 4)));
        *(f16x8*)&Ch[(size_t)(row0 + p * 128 + row) * ldc + col0 +
                     ((lane & 15) << 3)] = d;
      }
    }
  }
#undef ST_A
#undef ST_B
}

// ===========================================================================
// 128x128 m97-style GEMM (validated R1) for qk / scores / av / Wo.
// ===========================================================================
#define BM 128
#define BN 128
#define BK 32

template <int EPI>
__global__ void __launch_bounds__(256, 2) gemm_bt(
    const _Float16* __restrict__ A, long sA,
    const _Float16* __restrict__ Bt, long sB,
    void* __restrict__ Cp, long sC,
    int M, int N, int K, int lda, int ldb, int ldc, int causal,
    const _Float16* __restrict__ U) {
  int bm = blockIdx.x, bn = blockIdx.y, bz = blockIdx.z;
  if (EPI == EPI_SCORES && bn > bm) return;
  A += (size_t)bz * sA;
  Bt += (size_t)bz * sB;

  int Keff = K;
  if (causal == 2) {
    int km = (bm + 1) * BM;
    Keff = km < K ? km : K;
  }

  __shared__ __align__(16) _Float16 As[BM * BK];
  __shared__ __align__(16) _Float16 Bs[BN * BK];

  int tid = threadIdx.x;
  int lane = tid & 63, wave = tid >> 6;
  int wr = (wave >> 1) << 6;
  int wc = (wave & 1) << 6;
  int row0 = bm * BM, col0 = bn * BN;
  int fr = lane & 15;
  int kg = lane >> 4;
  int srow = lane >> 2;
  int scol = (lane & 3) << 3;

  f32x4 acc[4][4];
#pragma unroll
  for (int i = 0; i < 4; i++)
#pragma unroll
    for (int j = 0; j < 4; j++)
#pragma unroll
      for (int e = 0; e < 4; e++) acc[i][j][e] = 0.f;

  const f16x8* As8 = (const f16x8*)As;
  const f16x8* Bs8 = (const f16x8*)Bs;

  for (int k0 = 0; k0 < Keff; k0 += BK) {
    __syncthreads();
#pragma unroll
    for (int i = 0; i < 2; i++) {
      int rb = (wave * 2 + i) * 16;
      load_lds16(A + (size_t)(row0 + rb + srow) * lda + k0 + scol,
                 (void*)&As[rb * BK]);
      load_lds16(Bt + (size_t)(col0 + rb + srow) * ldb + k0 + scol,
                 (void*)&Bs[rb * BK]);
    }
    asm volatile("s_waitcnt vmcnt(0)" ::: "memory");
    __syncthreads();

    f16x8 af[4], bf[4];
#pragma unroll
    for (int m = 0; m < 4; m++)
      af[m] = As8[(size_t)(wr + m * 16 + fr) * (BK / 8) + kg];
#pragma unroll
    for (int n = 0; n < 4; n++)
      bf[n] = Bs8[(size_t)(wc + n * 16 + fr) * (BK / 8) + kg];
#pragma unroll
    for (int m = 0; m < 4; m++)
#pragma unroll
      for (int n = 0; n < 4; n++)
        acc[m][n] =
            __builtin_amdgcn_mfma_f32_16x16x32_f16(af[m], bf[n], acc[m][n], 0, 0, 0);
  }

#pragma unroll
  for (int m = 0; m < 4; m++) {
    int gr0 = row0 + wr + m * 16 + (kg << 2);
#pragma unroll
    for (int n = 0; n < 4; n++) {
      int gc = col0 + wc + n * 16 + fr;
#pragma unroll
      for (int r = 0; r < 4; r++) {
        float v = acc[m][n][r];
        size_t ci = (size_t)(gr0 + r) * ldc + gc;
        if (EPI == EPI_F32) {
          ((float*)Cp + (size_t)bz * sC)[ci] = v;
        } else if (EPI == EPI_SILU) {
          ((_Float16*)Cp + (size_t)bz * sC)[ci] =
              (_Float16)(v / (1.f + expf(-v)));
        } else if (EPI == EPI_SCORES) {
          float s = v * 0.08838834764831845f;  // 1/sqrt(128)
          s = fmaxf(s, 0.f);
          s = (gc <= gr0 + r) ? s * s : 0.f;
          ((_Float16*)Cp + (size_t)bz * sC)[ci] = (_Float16)s;
        } else if (EPI == EPI_GATED) {  // gh = u * (attn@v)
          const _Float16* Ub = U + (size_t)bz * sC;
          ((_Float16*)Cp + (size_t)bz * sC)[ci] = (_Float16)((float)Ub[ci] * v);
        } else {  // EPI_RESID
          ((float*)Cp)[ci] += v;
        }
      }
    }
  }
}

__global__ void __launch_bounds__(256) ln_kernel(const float* __restrict__ x,
                                                 const float* __restrict__ g,
                                                 const float* __restrict__ b,
                                                 _Float16* __restrict__ out) {
  int row = blockIdx.x, tid = threadIdx.x;
  float4 v = ((const float4*)(x + (size_t)row * Dd))[tid];
  float s = v.x + v.y + v.z + v.w;
  float q = v.x * v.x + v.y * v.y + v.z * v.z + v.w * v.w;
#pragma unroll
  for (int off = 32; off > 0; off >>= 1) {
    s += __shfl_down(s, off, 64);
    q += __shfl_down(q, off, 64);
  }
  __shared__ float ss[4], sq[4];
  int lane = tid & 63, wv = tid >> 6;
  if (lane == 0) { ss[wv] = s; sq[wv] = q; }
  __syncthreads();
  s = ss[0] + ss[1] + ss[2] + ss[3];
  q = sq[0] + sq[1] + sq[2] + sq[3];
  float mu = s * (1.f / Dd);
  float var = q * (1.f / Dd) - mu * mu;
  float rs = rsqrtf(var + 1e-5f);
  float4 gg = ((const float4*)g)[tid];
  float4 bb = ((const float4*)b)[tid];
  f16x4 o;
  o[0] = (_Float16)((v.x - mu) * rs * gg.x + bb.x);
  o[1] = (_Float16)((v.y - mu) * rs * gg.y + bb.y);
  o[2] = (_Float16)((v.z - mu) * rs * gg.z + bb.z);
  o[3] = (_Float16)((v.w - mu) * rs * gg.w + bb.w);
  ((f16x4*)(out + (size_t)row * Dd))[tid] = o;
}

__global__ void embed_kernel(const int* __restrict__ toks,
                             const float* __restrict__ emb,
                             float* __restrict__ x) {
  int row = blockIdx.x, tid = threadIdx.x;
  long t = toks[row];
  ((float4*)(x + (size_t)row * Dd))[tid] =
      ((const float4*)(emb + (size_t)t * Dd))[tid];
}

__global__ void rope_table_kernel(float* __restrict__ cosT,
                                  float* __restrict__ sinT) {
  int idx = blockIdx.x * 256 + threadIdx.x;  // T*64
  int t = idx >> 6, i = idx & 63;
  float inv = powf(10000.f, (float)(2 * i) * (-1.f / 128.f));
  float a = (float)t * inv;
  cosT[idx] = cosf(a);
  sinT[idx] = sinf(a);
}

__global__ void rope_kernel(const float* __restrict__ pre,
                            _Float16* __restrict__ o16,
                            const float* __restrict__ cosT,
                            const float* __restrict__ sinT) {
  int row = blockIdx.x * 4 + threadIdx.y;
  int i = threadIdx.x;
  int z = blockIdx.y;
  const float* p = pre + (size_t)z * BT * Ss + (size_t)row * Ss;
  _Float16* o = o16 + (size_t)z * BT * Ss + (size_t)row * Ss;
  int t = row & (Tt - 1);
  float c = cosT[t * 64 + i], sn = sinT[t * 64 + i];
  float x1 = p[i], x2 = p[i + 64];
  o[i] = (_Float16)(x1 * c - x2 * sn);
  o[i + 64] = (_Float16)(x1 * sn + x2 * c);
}

// out(C x R) = transpose(in(R x C)), convert to f16.
template <typename TIn>
__global__ void transconv_kernel(const TIn* __restrict__ in,
                                 _Float16* __restrict__ out, int R, int C,
                                 long s_in, long s_out) {
  __shared__ float tile[64][65];
  in += (size_t)blockIdx.z * s_in;
  out += (size_t)blockIdx.z * s_out;
  int r0 = blockIdx.y * 64, c0 = blockIdx.x * 64;
  int tx = threadIdx.x & 63, ty = threadIdx.x >> 6;
#pragma unroll
  for (int p = 0; p < 16; p++) {
    int r = p * 4 + ty;
    tile[r][tx] = (float)in[(size_t)(r0 + r) * C + c0 + tx];
  }
  __syncthreads();
#pragma unroll
  for (int p = 0; p < 16; p++) {
    int r = p * 4 + ty;
    out[(size_t)(c0 + r) * R + r0 + tx] = (_Float16)tile[tx][r];
  }
}

extern "C" void kernel_launch(void* const* d_in, const int* in_sizes, int n_in,
                              void* d_out, int out_size, void* d_ws,
                              size_t ws_size, hipStream_t stream) {
  const int*   tokens = (const int*)d_in[0];
  const float* emb    = (const float*)d_in[1];
  const float* Wu     = (const float*)d_in[2];
  const float* Wv     = (const float*)d_in[3];
  const float* Wq     = (const float*)d_in[4];
  const float* Wk     = (const float*)d_in[5];
  const float* Wo     = (const float*)d_in[6];
  const float* ln_g   = (const float*)d_in[7];
  const float* ln_b   = (const float*)d_in[8];
  const float* lnf_g  = (const float*)d_in[9];
  const float* lnf_b  = (const float*)d_in[10];
  const float* Wlm    = (const float*)d_in[11];
  float* out = (float*)d_out;
  (void)in_sizes; (void)n_in; (void)out_size;

  char* wsp = (char*)d_ws;
  size_t off = 0;
  auto alloc = [&](size_t bytes) -> void* {
    void* p = wsp + off;
    off = (off + bytes + 255) & ~(size_t)255;
    return p;
  };

  float*    x     = (float*)alloc((size_t)BT * Dd * 4);
  _Float16* xn    = (_Float16*)alloc((size_t)BT * Dd * 2);
  _Float16* uvh   = (_Float16*)alloc((size_t)2 * BT * Ee * 2);
  _Float16* vT    = (_Float16*)alloc((size_t)Bz * Ee * Tt * 2);
  float*    qkpre = (float*)alloc((size_t)2 * BT * Ss * 4);
  _Float16* qkh   = (_Float16*)alloc((size_t)2 * BT * Ss * 2);
  _Float16* attn  = (_Float16*)alloc((size_t)Bz * Tt * Tt * 2);
  _Float16* gh    = (_Float16*)alloc((size_t)BT * Ee * 2);
  float*    cosT  = (float*)alloc((size_t)Tt * 64 * 4);
  float*    sinT  = (float*)alloc((size_t)Tt * 64 * 4);
  _Float16* WuvT  = (_Float16*)alloc((size_t)2 * Ll * Ee * Dd * 2);
  _Float16* WqkT  = (_Float16*)alloc((size_t)2 * Ll * Ss * Ee * 2);
  _Float16* WoT   = (_Float16*)alloc((size_t)Ll * Dd * Ee * 2);
  _Float16* WlmT  = (_Float16*)alloc((size_t)Vv * Dd * 2);
  if (off > ws_size) return;

  transconv_kernel<float><<<dim3(Ee / 64, Dd / 64, Ll), 256, 0, stream>>>(
      Wu, WuvT, Dd, Ee, (long)Dd * Ee, (long)Ee * Dd);
  transconv_kernel<float><<<dim3(Ee / 64, Dd / 64, Ll), 256, 0, stream>>>(
      Wv, WuvT + (size_t)Ll * Ee * Dd, Dd, Ee, (long)Dd * Ee, (long)Ee * Dd);
  transconv_kernel<float><<<dim3(Ss / 64, Ee / 64, Ll), 256, 0, stream>>>(
      Wq, WqkT, Ee, Ss, (long)Ee * Ss, (long)Ss * Ee);
  transconv_kernel<float><<<dim3(Ss / 64, Ee / 64, Ll), 256, 0, stream>>>(
      Wk, WqkT + (size_t)Ll * Ss * Ee, Ee, Ss, (long)Ee * Ss, (long)Ss * Ee);
  transconv_kernel<float><<<dim3(Dd / 64, Ee / 64, Ll), 256, 0, stream>>>(
      Wo, WoT, Ee, Dd, (long)Ee * Dd, (long)Dd * Ee);
  transconv_kernel<float><<<dim3(Vv / 64, Dd / 64, 1), 256, 0, stream>>>(
      Wlm, WlmT, Dd, Vv, 0, 0);

  rope_table_kernel<<<(Tt * 64) / 256, 256, 0, stream>>>(cosT, sinT);
  embed_kernel<<<BT, 256, 0, stream>>>(tokens, emb, x);

  for (int l = 0; l < Ll; l++) {
    ln_kernel<<<BT, 256, 0, stream>>>(x, ln_g + (size_t)l * Dd,
                                      ln_b + (size_t)l * Dd, xn);
    // u = silu(xn@Wu), v = silu(xn@Wv)  -- 256x128 kernel, 2 blocks/CU
    gemm256<EPI_SILU><<<dim3((BT / 256) * (Ee / 128), 1, 2), 512, 0, stream>>>(
        xn, 0, WuvT + (size_t)l * Ee * Dd, (long)Ll * Ee * Dd, (void*)uvh,
        (long)BT * Ee, BT, Ee, Dd, Dd, Dd, Ee);
    // q_pre = u@Wq, k_pre = v@Wk
    gemm_bt<EPI_F32><<<dim3(BT / BM, Ss / BN, 2), 256, 0, stream>>>(
        uvh, (long)BT * Ee, WqkT + (size_t)l * Ss * Ee, (long)Ll * Ss * Ee,
        (void*)qkpre, (long)BT * Ss, BT, Ss, Ee, Ee, Ee, Ss, 0, nullptr);
    rope_kernel<<<dim3(BT / 4, 2), dim3(64, 4), 0, stream>>>(qkpre, qkh, cosT,
                                                             sinT);
    transconv_kernel<_Float16><<<dim3(Ee / 64, Tt / 64, Bz), 256, 0, stream>>>(
        uvh + (size_t)BT * Ee, vT, Tt, Ee, (long)Tt * Ee, (long)Ee * Tt);
    // scores = relu(mask(q@k^T * scale))^2
    gemm_bt<EPI_SCORES><<<dim3(Tt / BM, Tt / BN, Bz), 256, 0, stream>>>(
        qkh, (long)Tt * Ss, qkh + (size_t)BT * Ss, (long)Tt * Ss, (void*)attn,
        (long)Tt * Tt, Tt, Tt, Ss, Ss, Ss, Tt, 0, nullptr);
    // gh = u * (attn @ v)   (gate fused into av epilogue)
    gemm_bt<EPI_GATED><<<dim3(Tt / BM, Ee / BN, Bz), 256, 0, stream>>>(
        attn, (long)Tt * Tt, vT, (long)Ee * Tt, (void*)gh, (long)Tt * Ee, Tt,
        Ee, Tt, Tt, Tt, Ee, 2, uvh);
    // x += gh @ Wo
    gemm_bt<EPI_RESID><<<dim3(BT / BM, Dd / BN, 1), 256, 0, stream>>>(
        gh, 0, WoT + (size_t)l * Dd * Ee, 0, (void*)x, 0, BT, Dd, Ee, Ee, Ee,
        Dd, 0, nullptr);
  }

  ln_kernel<<<BT, 256, 0, stream>>>(x, lnf_g, lnf_b, xn);
  // logits = xn @ Wlm   -- 256x128 kernel, 2 blocks/CU
  gemm256<EPI_F32><<<dim3((BT / 256) * (Vv / 128), 1, 1), 512, 0, stream>>>(
      xn, 0, WlmT, 0, (void*)out, 0, BT, Vv, Dd, Dd, Dd, Vv);
}

// Round 9
// 1292.961 us; speedup vs baseline: 1.0746x; 1.0746x over previous
//
#include <hip/hip_runtime.h>
#include <math.h>

// ---------------------------------------------------------------------------
// GatedAttentionTransformer  (B=2, T=2048, D=1024, E=2048, S=128, L=4, V=32000)
// Round 9: revert gemm256 to R4 (best verified); add non-temporal stores for
//          the head's f32 output + weight-transpose outputs (write-once data
//          was evicting A/B panels from L2/L3 -> 290MB avoidable re-fetch).
// ---------------------------------------------------------------------------

#define Bz 2
#define Tt 2048
#define Dd 1024
#define Ee 2048
#define Ss 128
#define Ll 4
#define Vv 32000
#define BT (Bz * Tt)   // 4096

typedef __attribute__((ext_vector_type(8))) _Float16 f16x8;
typedef __attribute__((ext_vector_type(4))) _Float16 f16x4;
typedef __attribute__((ext_vector_type(4))) float    f32x4;

__device__ __forceinline__ void load_lds16(const void* g, void* l) {
  __builtin_amdgcn_global_load_lds(
      (const __attribute__((address_space(1))) void*)g,
      (__attribute__((address_space(3))) void*)l, 16, 0, 0);
}

#define FENCE asm volatile("" ::: "memory")
#define BARRIER do { FENCE; __builtin_amdgcn_s_barrier(); FENCE; } while (0)
#define LGKM0 do { asm volatile("s_waitcnt lgkmcnt(0)" ::: "memory"); \
                   __builtin_amdgcn_sched_barrier(0); } while (0)

enum { EPI_F32 = 0, EPI_SILU = 1, EPI_SCORES = 2, EPI_RESID = 3, EPI_GATED = 4 };

// bijective XCD swizzle (m204)
__device__ __forceinline__ int xcd_swz(int id, int nwg) {
  int q = nwg >> 3, r = nwg & 7;
  int x = id & 7, o = id >> 3;
  return (x < r ? x * (q + 1) : r * (q + 1) + (x - r) * q) + o;
}

// ===========================================================================
// 256x256 tile, BK=64, 8 waves (2M x 4N), 4 phases/K-tile, counted vmcnt,
// granule-XOR LDS swizzle (R4-verified). Epilogue: LDS-bounce -> coalesced
// full-row stores; f32 path streams via non-temporal stores.
// Requires M%256==0, N%256==0, K%64==0, K>=128.
// ===========================================================================
template <int EPI>
__global__ void __launch_bounds__(512) gemm256(
    const _Float16* __restrict__ A, long sA,
    const _Float16* __restrict__ Bt, long sB,
    void* __restrict__ Cp, long sC,
    int M, int N, int K, int lda, int ldb, int ldc) {
  const int bz = blockIdx.z;
  A += (size_t)bz * sA;
  Bt += (size_t)bz * sB;

  const int nbm = M >> 8;
  const int id = xcd_swz(blockIdx.x, gridDim.x);
  const int bm = id % nbm, bn = id / nbm;
  const int row0 = bm << 8, col0 = bn << 8;

  // 128 KiB shared: K-loop = A dbuf (64K) | B dbuf (64K); epilogue = bounce
  __shared__ __align__(16) char smem[131072];
  _Float16* const Abuf0 = (_Float16*)smem;             // [2][16384]
  _Float16* const Bbuf0 = (_Float16*)(smem + 65536);   // [2][16384]

  const int tid = threadIdx.x, lane = tid & 63, w = tid >> 6;
  const int mu = w >> 2, nu = w & 3;     // wave grid 2(M) x 4(N)
  const int fr = lane & 15, kg = lane >> 4;
  // staging: each load instr = one 64-row x 64-col quarter (8 KB)
  const int srow = (w << 3) + (lane >> 3);           // row in quarter
  const int sg = (lane & 7) ^ ((lane >> 3) & 7);     // pre-swizzled src granule
  const _Float16* Asrc = A + (size_t)(row0 + srow) * lda + sg * 8;
  const _Float16* Bsrc = Bt + (size_t)(col0 + srow) * ldb + sg * 8;
  // swizzled read granule offsets (elements), ks = 0,1
  const int gx[2] = { ((kg) ^ (fr & 7)) << 3, ((4 + kg) ^ (fr & 7)) << 3 };

#define ST_A(BUF, KT, Q) load_lds16(Asrc + (size_t)(Q) * 64 * lda + (size_t)(KT) * 64, \
                                    (void*)&Abuf0[(BUF) * 16384 + (Q) * 4096 + (w << 9)])
#define ST_B(BUF, KT, Q) load_lds16(Bsrc + (size_t)(Q) * 64 * ldb + (size_t)(KT) * 64, \
                                    (void*)&Bbuf0[(BUF) * 16384 + (Q) * 4096 + (w << 9)])
#define RD_A(BUF, MH)                                                          \
  { _Pragma("unroll") for (int j = 0; j < 4; ++j)                              \
    _Pragma("unroll") for (int ks = 0; ks < 2; ++ks)                           \
      af[j][ks] = *(const f16x8*)&Abuf0[(BUF) * 16384 +                        \
          (mu * 128 + (MH) * 64 + j * 16 + fr) * 64 + gx[ks]]; }
#define RD_B(BUF, NH, BQ)                                                      \
  { _Pragma("unroll") for (int i = 0; i < 2; ++i)                              \
    _Pragma("unroll") for (int ks = 0; ks < 2; ++ks)                           \
      BQ[i][ks] = *(const f16x8*)&Bbuf0[(BUF) * 16384 +                        \
          (nu * 64 + (NH) * 32 + i * 16 + fr) * 64 + gx[ks]]; }
#define MFMA_Q(MH, NH, BQ)                                                     \
  { _Pragma("unroll") for (int j = 0; j < 4; ++j)                              \
    _Pragma("unroll") for (int i = 0; i < 2; ++i)                              \
    _Pragma("unroll") for (int ks = 0; ks < 2; ++ks)                           \
      acc[(MH) * 4 + j][(NH) * 2 + i] = __builtin_amdgcn_mfma_f32_16x16x32_f16( \
          af[j][ks], BQ[i][ks], acc[(MH) * 4 + j][(NH) * 2 + i], 0, 0, 0); }

  f32x4 acc[8][4];
#pragma unroll
  for (int m = 0; m < 8; ++m)
#pragma unroll
    for (int n = 0; n < 4; ++n)
#pragma unroll
      for (int e = 0; e < 4; ++e) acc[m][n][e] = 0.f;

  f16x8 af[4][2], bfA[2][2], bfB[2][2];

  const int NT = K >> 6;
  // prologue: stage tile 0 -> buf0
  ST_B(0, 0, 0); ST_B(0, 0, 1); ST_B(0, 0, 2); ST_B(0, 0, 3);
  ST_A(0, 0, 0); ST_A(0, 0, 2); ST_A(0, 0, 1); ST_A(0, 0, 3);
  asm volatile("s_waitcnt vmcnt(2)" ::: "memory");
  BARRIER;

  for (int t = 0; t < NT; ++t) {
    const int b = t & 1, nb = b ^ 1;
    const int kn = (t + 1 < NT) ? t + 1 : t;  // tail: re-stage (never read)
    // ---- P0: quadrant (mh0, nh0)
    RD_A(b, 0);
    RD_B(b, 0, bfA);
    ST_B(nb, kn, 0); ST_B(nb, kn, 1);
    BARRIER;
    LGKM0;
    __builtin_amdgcn_s_setprio(1); MFMA_Q(0, 0, bfA); __builtin_amdgcn_s_setprio(0);
    BARRIER;
    // ---- P1: (mh0, nh1)
    RD_B(b, 1, bfB);
    ST_B(nb, kn, 2); ST_B(nb, kn, 3);
    BARRIER;
    LGKM0;
    __builtin_amdgcn_s_setprio(1); MFMA_Q(0, 1, bfB); __builtin_amdgcn_s_setprio(0);
    asm volatile("s_waitcnt vmcnt(4)" ::: "memory");
    BARRIER;
    // ---- P2: (mh1, nh0)
    RD_A(b, 1);
    ST_A(nb, kn, 0); ST_A(nb, kn, 2);
    BARRIER;
    LGKM0;
    __builtin_amdgcn_s_setprio(1); MFMA_Q(1, 0, bfA); __builtin_amdgcn_s_setprio(0);
    BARRIER;
    // ---- P3: (mh1, nh1)
    ST_A(nb, kn, 1); ST_A(nb, kn, 3);
    BARRIER;
    LGKM0;
    __builtin_amdgcn_s_setprio(1); MFMA_Q(1, 1, bfB); __builtin_amdgcn_s_setprio(0);
    asm volatile("s_waitcnt vmcnt(2)" ::: "memory");
    BARRIER;
  }
  asm volatile("s_waitcnt vmcnt(0)" ::: "memory");

  // ---- epilogue: LDS bounce -> coalesced full-row stores --------------------
  if (EPI == EPI_F32) {
    float* Cb = (float*)Cp + (size_t)bz * sC;
#pragma unroll
    for (int p = 0; p < 2; ++p) {   // pass p: tile rows [p*128, p*128+128)
      __syncthreads();
      if (mu == p) {
#pragma unroll
        for (int m = 0; m < 8; ++m)
#pragma unroll
          for (int n = 0; n < 4; ++n) {
            int rl = m * 16 + (kg << 2);
            int col = nu * 64 + n * 16 + fr;
#pragma unroll
            for (int r = 0; r < 4; ++r) {
              int row = rl + r;
              *(float*)(smem + (row << 10) + ((col << 2) ^ ((row & 7) << 4))) =
                  acc[m][n][r];
            }
          }
      }
      __syncthreads();
#pragma unroll
      for (int j = 0; j < 16; ++j) {
        int row = j * 8 + w;        // 8 rows per round (one per wave)
        f32x4 d = *(const f32x4*)(smem + (row << 10) +
                                  ((lane << 4) ^ ((row & 7) << 4)));
        // output is never re-read: stream past the caches
        __builtin_nontemporal_store(
            d, (f32x4*)&Cb[(size_t)(row0 + p * 128 + row) * ldc + col0 +
                           (lane << 2)]);
      }
    }
  } else {  // EPI_SILU: f16 output, 256x256x2B = 128K, single pass
    _Float16* Ch = (_Float16*)Cp + (size_t)bz * sC;
    __syncthreads();
#pragma unroll
    for (int m = 0; m < 8; ++m)
#pragma unroll
      for (int n = 0; n < 4; ++n) {
        int rl = mu * 128 + m * 16 + (kg << 2);
        int col = nu * 64 + n * 16 + fr;
#pragma unroll
        for (int r = 0; r < 4; ++r) {
          int row = rl + r;
          float v = acc[m][n][r];
          *(_Float16*)(smem + (row << 9) + ((col << 1) ^ ((row & 7) << 4))) =
              (_Float16)(v / (1.f + expf(-v)));
        }
      }
    __syncthreads();
#pragma unroll
    for (int j = 0; j < 16; ++j) {
      int row = j * 16 + w * 2 + (lane >> 5);  // 16 rows per round
      int g = lane & 31;
      f16x8 d = *(const f16x8*)(smem + (row << 9) +
                                ((g << 4) ^ ((row & 7) << 4)));
      *(f16x8*)&Ch[(size_t)(row0 + row) * ldc + col0 + (g << 3)] = d;
    }
  }
#undef ST_A
#undef ST_B
#undef RD_A
#undef RD_B
#undef MFMA_Q
}

// ===========================================================================
// 128x128 m97-style GEMM (validated R1) for qk / scores / av / Wo.
// ===========================================================================
#define BM 128
#define BN 128
#define BK 32

template <int EPI>
__global__ void __launch_bounds__(256, 2) gemm_bt(
    const _Float16* __restrict__ A, long sA,
    const _Float16* __restrict__ Bt, long sB,
    void* __restrict__ Cp, long sC,
    int M, int N, int K, int lda, int ldb, int ldc, int causal,
    const _Float16* __restrict__ U) {
  int bm = blockIdx.x, bn = blockIdx.y, bz = blockIdx.z;
  if (EPI == EPI_SCORES && bn > bm) return;
  A += (size_t)bz * sA;
  Bt += (size_t)bz * sB;

  int Keff = K;
  if (causal == 2) {
    int km = (bm + 1) * BM;
    Keff = km < K ? km : K;
  }

  __shared__ __align__(16) _Float16 As[BM * BK];
  __shared__ __align__(16) _Float16 Bs[BN * BK];

  int tid = threadIdx.x;
  int lane = tid & 63, wave = tid >> 6;
  int wr = (wave >> 1) << 6;
  int wc = (wave & 1) << 6;
  int row0 = bm * BM, col0 = bn * BN;
  int fr = lane & 15;
  int kg = lane >> 4;
  int srow = lane >> 2;
  int scol = (lane & 3) << 3;

  f32x4 acc[4][4];
#pragma unroll
  for (int i = 0; i < 4; i++)
#pragma unroll
    for (int j = 0; j < 4; j++)
#pragma unroll
      for (int e = 0; e < 4; e++) acc[i][j][e] = 0.f;

  const f16x8* As8 = (const f16x8*)As;
  const f16x8* Bs8 = (const f16x8*)Bs;

  for (int k0 = 0; k0 < Keff; k0 += BK) {
    __syncthreads();
#pragma unroll
    for (int i = 0; i < 2; i++) {
      int rb = (wave * 2 + i) * 16;
      load_lds16(A + (size_t)(row0 + rb + srow) * lda + k0 + scol,
                 (void*)&As[rb * BK]);
      load_lds16(Bt + (size_t)(col0 + rb + srow) * ldb + k0 + scol,
                 (void*)&Bs[rb * BK]);
    }
    asm volatile("s_waitcnt vmcnt(0)" ::: "memory");
    __syncthreads();

    f16x8 af[4], bf[4];
#pragma unroll
    for (int m = 0; m < 4; m++)
      af[m] = As8[(size_t)(wr + m * 16 + fr) * (BK / 8) + kg];
#pragma unroll
    for (int n = 0; n < 4; n++)
      bf[n] = Bs8[(size_t)(wc + n * 16 + fr) * (BK / 8) + kg];
#pragma unroll
    for (int m = 0; m < 4; m++)
#pragma unroll
      for (int n = 0; n < 4; n++)
        acc[m][n] =
            __builtin_amdgcn_mfma_f32_16x16x32_f16(af[m], bf[n], acc[m][n], 0, 0, 0);
  }

#pragma unroll
  for (int m = 0; m < 4; m++) {
    int gr0 = row0 + wr + m * 16 + (kg << 2);
#pragma unroll
    for (int n = 0; n < 4; n++) {
      int gc = col0 + wc + n * 16 + fr;
#pragma unroll
      for (int r = 0; r < 4; r++) {
        float v = acc[m][n][r];
        size_t ci = (size_t)(gr0 + r) * ldc + gc;
        if (EPI == EPI_F32) {
          ((float*)Cp + (size_t)bz * sC)[ci] = v;
        } else if (EPI == EPI_SILU) {
          ((_Float16*)Cp + (size_t)bz * sC)[ci] =
              (_Float16)(v / (1.f + expf(-v)));
        } else if (EPI == EPI_SCORES) {
          float s = v * 0.08838834764831845f;  // 1/sqrt(128)
          s = fmaxf(s, 0.f);
          s = (gc <= gr0 + r) ? s * s : 0.f;
          ((_Float16*)Cp + (size_t)bz * sC)[ci] = (_Float16)s;
        } else if (EPI == EPI_GATED) {  // gh = u * (attn@v)
          const _Float16* Ub = U + (size_t)bz * sC;
          ((_Float16*)Cp + (size_t)bz * sC)[ci] = (_Float16)((float)Ub[ci] * v);
        } else {  // EPI_RESID
          ((float*)Cp)[ci] += v;
        }
      }
    }
  }
}

__global__ void __launch_bounds__(256) ln_kernel(const float* __restrict__ x,
                                                 const float* __restrict__ g,
                                                 const float* __restrict__ b,
                                                 _Float16* __restrict__ out) {
  int row = blockIdx.x, tid = threadIdx.x;
  float4 v = ((const float4*)(x + (size_t)row * Dd))[tid];
  float s = v.x + v.y + v.z + v.w;
  float q = v.x * v.x + v.y * v.y + v.z * v.z + v.w * v.w;
#pragma unroll
  for (int off = 32; off > 0; off >>= 1) {
    s += __shfl_down(s, off, 64);
    q += __shfl_down(q, off, 64);
  }
  __shared__ float ss[4], sq[4];
  int lane = tid & 63, wv = tid >> 6;
  if (lane == 0) { ss[wv] = s; sq[wv] = q; }
  __syncthreads();
  s = ss[0] + ss[1] + ss[2] + ss[3];
  q = sq[0] + sq[1] + sq[2] + sq[3];
  float mu = s * (1.f / Dd);
  float var = q * (1.f / Dd) - mu * mu;
  float rs = rsqrtf(var + 1e-5f);
  float4 gg = ((const float4*)g)[tid];
  float4 bb = ((const float4*)b)[tid];
  f16x4 o;
  o[0] = (_Float16)((v.x - mu) * rs * gg.x + bb.x);
  o[1] = (_Float16)((v.y - mu) * rs * gg.y + bb.y);
  o[2] = (_Float16)((v.z - mu) * rs * gg.z + bb.z);
  o[3] = (_Float16)((v.w - mu) * rs * gg.w + bb.w);
  ((f16x4*)(out + (size_t)row * Dd))[tid] = o;
}

__global__ void embed_kernel(const int* __restrict__ toks,
                             const float* __restrict__ emb,
                             float* __restrict__ x) {
  int row = blockIdx.x, tid = threadIdx.x;
  long t = toks[row];
  ((float4*)(x + (size_t)row * Dd))[tid] =
      ((const float4*)(emb + (size_t)t * Dd))[tid];
}

__global__ void rope_table_kernel(float* __restrict__ cosT,
                                  float* __restrict__ sinT) {
  int idx = blockIdx.x * 256 + threadIdx.x;  // T*64
  int t = idx >> 6, i = idx & 63;
  float inv = powf(10000.f, (float)(2 * i) * (-1.f / 128.f));
  float a = (float)t * inv;
  cosT[idx] = cosf(a);
  sinT[idx] = sinf(a);
}

__global__ void rope_kernel(const float* __restrict__ pre,
                            _Float16* __restrict__ o16,
                            const float* __restrict__ cosT,
                            const float* __restrict__ sinT) {
  int row = blockIdx.x * 4 + threadIdx.y;
  int i = threadIdx.x;
  int z = blockIdx.y;
  const float* p = pre + (size_t)z * BT * Ss + (size_t)row * Ss;
  _Float16* o = o16 + (size_t)z * BT * Ss + (size_t)row * Ss;
  int t = row & (Tt - 1);
  float c = cosT[t * 64 + i], sn = sinT[t * 64 + i];
  float x1 = p[i], x2 = p[i + 64];
  o[i] = (_Float16)(x1 * c - x2 * sn);
  o[i + 64] = (_Float16)(x1 * sn + x2 * c);
}

// out(C x R) = transpose(in(R x C)), convert to f16.
// float instantiation = weight transposes (write-once, read-late): nt stores.
template <typename TIn>
__global__ void transconv_kernel(const TIn* __restrict__ in,
                                 _Float16* __restrict__ out, int R, int C,
                                 long s_in, long s_out) {
  __shared__ float tile[64][65];
  in += (size_t)blockIdx.z * s_in;
  out += (size_t)blockIdx.z * s_out;
  int r0 = blockIdx.y * 64, c0 = blockIdx.x * 64;
  int tx = threadIdx.x & 63, ty = threadIdx.x >> 6;
#pragma unroll
  for (int p = 0; p < 16; p++) {
    int r = p * 4 + ty;
    tile[r][tx] = (float)in[(size_t)(r0 + r) * C + c0 + tx];
  }
  __syncthreads();
#pragma unroll
  for (int p = 0; p < 16; p++) {
    int r = p * 4 + ty;
    _Float16 v = (_Float16)tile[tx][r];
    _Float16* dst = &out[(size_t)(c0 + r) * R + r0 + tx];
    if (sizeof(TIn) == 4) {
      __builtin_nontemporal_store(v, dst);   // weights: don't pollute L2/L3
    } else {
      *dst = v;                              // vT: consumed immediately, cache
    }
  }
}

extern "C" void kernel_launch(void* const* d_in, const int* in_sizes, int n_in,
                              void* d_out, int out_size, void* d_ws,
                              size_t ws_size, hipStream_t stream) {
  const int*   tokens = (const int*)d_in[0];
  const float* emb    = (const float*)d_in[1];
  const float* Wu     = (const float*)d_in[2];
  const float* Wv     = (const float*)d_in[3];
  const float* Wq     = (const float*)d_in[4];
  const float* Wk     = (const float*)d_in[5];
  const float* Wo     = (const float*)d_in[6];
  const float* ln_g   = (const float*)d_in[7];
  const float* ln_b   = (const float*)d_in[8];
  const float* lnf_g  = (const float*)d_in[9];
  const float* lnf_b  = (const float*)d_in[10];
  const float* Wlm    = (const float*)d_in[11];
  float* out = (float*)d_out;
  (void)in_sizes; (void)n_in; (void)out_size;

  char* wsp = (char*)d_ws;
  size_t off = 0;
  auto alloc = [&](size_t bytes) -> void* {
    void* p = wsp + off;
    off = (off + bytes + 255) & ~(size_t)255;
    return p;
  };

  float*    x     = (float*)alloc((size_t)BT * Dd * 4);
  _Float16* xn    = (_Float16*)alloc((size_t)BT * Dd * 2);
  _Float16* uvh   = (_Float16*)alloc((size_t)2 * BT * Ee * 2);
  _Float16* vT    = (_Float16*)alloc((size_t)Bz * Ee * Tt * 2);
  float*    qkpre = (float*)alloc((size_t)2 * BT * Ss * 4);
  _Float16* qkh   = (_Float16*)alloc((size_t)2 * BT * Ss * 2);
  _Float16* attn  = (_Float16*)alloc((size_t)Bz * Tt * Tt * 2);
  _Float16* gh    = (_Float16*)alloc((size_t)BT * Ee * 2);
  float*    cosT  = (float*)alloc((size_t)Tt * 64 * 4);
  float*    sinT  = (float*)alloc((size_t)Tt * 64 * 4);
  _Float16* WuvT  = (_Float16*)alloc((size_t)2 * Ll * Ee * Dd * 2);
  _Float16* WqkT  = (_Float16*)alloc((size_t)2 * Ll * Ss * Ee * 2);
  _Float16* WoT   = (_Float16*)alloc((size_t)Ll * Dd * Ee * 2);
  _Float16* WlmT  = (_Float16*)alloc((size_t)Vv * Dd * 2);
  if (off > ws_size) return;

  transconv_kernel<float><<<dim3(Ee / 64, Dd / 64, Ll), 256, 0, stream>>>(
      Wu, WuvT, Dd, Ee, (long)Dd * Ee, (long)Ee * Dd);
  transconv_kernel<float><<<dim3(Ee / 64, Dd / 64, Ll), 256, 0, stream>>>(
      Wv, WuvT + (size_t)Ll * Ee * Dd, Dd, Ee, (long)Dd * Ee, (long)Ee * Dd);
  transconv_kernel<float><<<dim3(Ss / 64, Ee / 64, Ll), 256, 0, stream>>>(
      Wq, WqkT, Ee, Ss, (long)Ee * Ss, (long)Ss * Ee);
  transconv_kernel<float><<<dim3(Ss / 64, Ee / 64, Ll), 256, 0, stream>>>(
      Wk, WqkT + (size_t)Ll * Ss * Ee, Ee, Ss, (long)Ee * Ss, (long)Ss * Ee);
  transconv_kernel<float><<<dim3(Dd / 64, Ee / 64, Ll), 256, 0, stream>>>(
      Wo, WoT, Ee, Dd, (long)Ee * Dd, (long)Dd * Ee);
  transconv_kernel<float><<<dim3(Vv / 64, Dd / 64, 1), 256, 0, stream>>>(
      Wlm, WlmT, Dd, Vv, 0, 0);

  rope_table_kernel<<<(Tt * 64) / 256, 256, 0, stream>>>(cosT, sinT);
  embed_kernel<<<BT, 256, 0, stream>>>(tokens, emb, x);

  for (int l = 0; l < Ll; l++) {
    ln_kernel<<<BT, 256, 0, stream>>>(x, ln_g + (size_t)l * Dd,
                                      ln_b + (size_t)l * Dd, xn);
    // u = silu(xn@Wu), v = silu(xn@Wv)  -- 256^2 kernel
    gemm256<EPI_SILU><<<dim3((BT / 256) * (Ee / 256), 1, 2), 512, 0, stream>>>(
        xn, 0, WuvT + (size_t)l * Ee * Dd, (long)Ll * Ee * Dd, (void*)uvh,
        (long)BT * Ee, BT, Ee, Dd, Dd, Dd, Ee);
    // q_pre = u@Wq, k_pre = v@Wk
    gemm_bt<EPI_F32><<<dim3(BT / BM, Ss / BN, 2), 256, 0, stream>>>(
        uvh, (long)BT * Ee, WqkT + (size_t)l * Ss * Ee, (long)Ll * Ss * Ee,
        (void*)qkpre, (long)BT * Ss, BT, Ss, Ee, Ee, Ee, Ss, 0, nullptr);
    rope_kernel<<<dim3(BT / 4, 2), dim3(64, 4), 0, stream>>>(qkpre, qkh, cosT,
                                                             sinT);
    transconv_kernel<_Float16><<<dim3(Ee / 64, Tt / 64, Bz), 256, 0, stream>>>(
        uvh + (size_t)BT * Ee, vT, Tt, Ee, (long)Tt * Ee, (long)Ee * Tt);
    // scores = relu(mask(q@k^T * scale))^2
    gemm_bt<EPI_SCORES><<<dim3(Tt / BM, Tt / BN, Bz), 256, 0, stream>>>(
        qkh, (long)Tt * Ss, qkh + (size_t)BT * Ss, (long)Tt * Ss, (void*)attn,
        (long)Tt * Tt, Tt, Tt, Ss, Ss, Ss, Tt, 0, nullptr);
    // gh = u * (attn @ v)   (gate fused into av epilogue)
    gemm_bt<EPI_GATED><<<dim3(Tt / BM, Ee / BN, Bz), 256, 0, stream>>>(
        attn, (long)Tt * Tt, vT, (long)Ee * Tt, (void*)gh, (long)Tt * Ee, Tt,
        Ee, Tt, Tt, Tt, Ee, 2, uvh);
    // x += gh @ Wo
    gemm_bt<EPI_RESID><<<dim3(BT / BM, Dd / BN, 1), 256, 0, stream>>>(
        gh, 0, WoT + (size_t)l * Dd * Ee, 0, (void*)x, 0, BT, Dd, Ee, Ee, Ee,
        Dd, 0, nullptr);
  }

  ln_kernel<<<BT, 256, 0, stream>>>(x, lnf_g, lnf_b, xn);
  // logits = xn @ Wlm   -- 256^2 kernel
  gemm256<EPI_F32><<<dim3((BT / 256) * (Vv / 256), 1, 1), 512, 0, stream>>>(
      xn, 0, WlmT, 0, (void*)out, 0, BT, Vv, Dd, Dd, Dd, Vv);
}

// Round 10
// 1179.055 us; speedup vs baseline: 1.1784x; 1.0966x over previous
//
#include <hip/hip_runtime.h>
#include <math.h>

// ---------------------------------------------------------------------------
// GatedAttentionTransformer  (B=2, T=2048, D=1024, E=2048, S=128, L=4, V=32000)
// Round 10: R9 + qk GEMM K-split x4 (64 -> 256 blocks; was 75% chip-idle),
//           partials reduced inside rope_kernel. Everything else unchanged.
// ---------------------------------------------------------------------------

#define Bz 2
#define Tt 2048
#define Dd 1024
#define Ee 2048
#define Ss 128
#define Ll 4
#define Vv 32000
#define BT (Bz * Tt)   // 4096
#define QKS 4          // qk K-split factor

typedef __attribute__((ext_vector_type(8))) _Float16 f16x8;
typedef __attribute__((ext_vector_type(4))) _Float16 f16x4;
typedef __attribute__((ext_vector_type(4))) float    f32x4;

__device__ __forceinline__ void load_lds16(const void* g, void* l) {
  __builtin_amdgcn_global_load_lds(
      (const __attribute__((address_space(1))) void*)g,
      (__attribute__((address_space(3))) void*)l, 16, 0, 0);
}

#define FENCE asm volatile("" ::: "memory")
#define BARRIER do { FENCE; __builtin_amdgcn_s_barrier(); FENCE; } while (0)
#define LGKM0 do { asm volatile("s_waitcnt lgkmcnt(0)" ::: "memory"); \
                   __builtin_amdgcn_sched_barrier(0); } while (0)

enum { EPI_F32 = 0, EPI_SILU = 1, EPI_SCORES = 2, EPI_RESID = 3, EPI_GATED = 4 };

// bijective XCD swizzle (m204)
__device__ __forceinline__ int xcd_swz(int id, int nwg) {
  int q = nwg >> 3, r = nwg & 7;
  int x = id & 7, o = id >> 3;
  return (x < r ? x * (q + 1) : r * (q + 1) + (x - r) * q) + o;
}

// ===========================================================================
// 256x256 tile, BK=64, 8 waves (2M x 4N), 4 phases/K-tile, counted vmcnt,
// granule-XOR LDS swizzle (R4-verified). Epilogue: LDS-bounce -> coalesced
// full-row stores; f32 path streams via non-temporal stores.
// ===========================================================================
template <int EPI>
__global__ void __launch_bounds__(512) gemm256(
    const _Float16* __restrict__ A, long sA,
    const _Float16* __restrict__ Bt, long sB,
    void* __restrict__ Cp, long sC,
    int M, int N, int K, int lda, int ldb, int ldc) {
  const int bz = blockIdx.z;
  A += (size_t)bz * sA;
  Bt += (size_t)bz * sB;

  const int nbm = M >> 8;
  const int id = xcd_swz(blockIdx.x, gridDim.x);
  const int bm = id % nbm, bn = id / nbm;
  const int row0 = bm << 8, col0 = bn << 8;

  __shared__ __align__(16) char smem[131072];
  _Float16* const Abuf0 = (_Float16*)smem;             // [2][16384]
  _Float16* const Bbuf0 = (_Float16*)(smem + 65536);   // [2][16384]

  const int tid = threadIdx.x, lane = tid & 63, w = tid >> 6;
  const int mu = w >> 2, nu = w & 3;
  const int fr = lane & 15, kg = lane >> 4;
  const int srow = (w << 3) + (lane >> 3);
  const int sg = (lane & 7) ^ ((lane >> 3) & 7);
  const _Float16* Asrc = A + (size_t)(row0 + srow) * lda + sg * 8;
  const _Float16* Bsrc = Bt + (size_t)(col0 + srow) * ldb + sg * 8;
  const int gx[2] = { ((kg) ^ (fr & 7)) << 3, ((4 + kg) ^ (fr & 7)) << 3 };

#define ST_A(BUF, KT, Q) load_lds16(Asrc + (size_t)(Q) * 64 * lda + (size_t)(KT) * 64, \
                                    (void*)&Abuf0[(BUF) * 16384 + (Q) * 4096 + (w << 9)])
#define ST_B(BUF, KT, Q) load_lds16(Bsrc + (size_t)(Q) * 64 * ldb + (size_t)(KT) * 64, \
                                    (void*)&Bbuf0[(BUF) * 16384 + (Q) * 4096 + (w << 9)])
#define RD_A(BUF, MH)                                                          \
  { _Pragma("unroll") for (int j = 0; j < 4; ++j)                              \
    _Pragma("unroll") for (int ks = 0; ks < 2; ++ks)                           \
      af[j][ks] = *(const f16x8*)&Abuf0[(BUF) * 16384 +                        \
          (mu * 128 + (MH) * 64 + j * 16 + fr) * 64 + gx[ks]]; }
#define RD_B(BUF, NH, BQ)                                                      \
  { _Pragma("unroll") for (int i = 0; i < 2; ++i)                              \
    _Pragma("unroll") for (int ks = 0; ks < 2; ++ks)                           \
      BQ[i][ks] = *(const f16x8*)&Bbuf0[(BUF) * 16384 +                        \
          (nu * 64 + (NH) * 32 + i * 16 + fr) * 64 + gx[ks]]; }
#define MFMA_Q(MH, NH, BQ)                                                     \
  { _Pragma("unroll") for (int j = 0; j < 4; ++j)                              \
    _Pragma("unroll") for (int i = 0; i < 2; ++i)                              \
    _Pragma("unroll") for (int ks = 0; ks < 2; ++ks)                           \
      acc[(MH) * 4 + j][(NH) * 2 + i] = __builtin_amdgcn_mfma_f32_16x16x32_f16( \
          af[j][ks], BQ[i][ks], acc[(MH) * 4 + j][(NH) * 2 + i], 0, 0, 0); }

  f32x4 acc[8][4];
#pragma unroll
  for (int m = 0; m < 8; ++m)
#pragma unroll
    for (int n = 0; n < 4; ++n)
#pragma unroll
      for (int e = 0; e < 4; ++e) acc[m][n][e] = 0.f;

  f16x8 af[4][2], bfA[2][2], bfB[2][2];

  const int NT = K >> 6;
  ST_B(0, 0, 0); ST_B(0, 0, 1); ST_B(0, 0, 2); ST_B(0, 0, 3);
  ST_A(0, 0, 0); ST_A(0, 0, 2); ST_A(0, 0, 1); ST_A(0, 0, 3);
  asm volatile("s_waitcnt vmcnt(2)" ::: "memory");
  BARRIER;

  for (int t = 0; t < NT; ++t) {
    const int b = t & 1, nb = b ^ 1;
    const int kn = (t + 1 < NT) ? t + 1 : t;
    RD_A(b, 0);
    RD_B(b, 0, bfA);
    ST_B(nb, kn, 0); ST_B(nb, kn, 1);
    BARRIER;
    LGKM0;
    __builtin_amdgcn_s_setprio(1); MFMA_Q(0, 0, bfA); __builtin_amdgcn_s_setprio(0);
    BARRIER;
    RD_B(b, 1, bfB);
    ST_B(nb, kn, 2); ST_B(nb, kn, 3);
    BARRIER;
    LGKM0;
    __builtin_amdgcn_s_setprio(1); MFMA_Q(0, 1, bfB); __builtin_amdgcn_s_setprio(0);
    asm volatile("s_waitcnt vmcnt(4)" ::: "memory");
    BARRIER;
    RD_A(b, 1);
    ST_A(nb, kn, 0); ST_A(nb, kn, 2);
    BARRIER;
    LGKM0;
    __builtin_amdgcn_s_setprio(1); MFMA_Q(1, 0, bfA); __builtin_amdgcn_s_setprio(0);
    BARRIER;
    ST_A(nb, kn, 1); ST_A(nb, kn, 3);
    BARRIER;
    LGKM0;
    __builtin_amdgcn_s_setprio(1); MFMA_Q(1, 1, bfB); __builtin_amdgcn_s_setprio(0);
    asm volatile("s_waitcnt vmcnt(2)" ::: "memory");
    BARRIER;
  }
  asm volatile("s_waitcnt vmcnt(0)" ::: "memory");

  if (EPI == EPI_F32) {
    float* Cb = (float*)Cp + (size_t)bz * sC;
#pragma unroll
    for (int p = 0; p < 2; ++p) {
      __syncthreads();
      if (mu == p) {
#pragma unroll
        for (int m = 0; m < 8; ++m)
#pragma unroll
          for (int n = 0; n < 4; ++n) {
            int rl = m * 16 + (kg << 2);
            int col = nu * 64 + n * 16 + fr;
#pragma unroll
            for (int r = 0; r < 4; ++r) {
              int row = rl + r;
              *(float*)(smem + (row << 10) + ((col << 2) ^ ((row & 7) << 4))) =
                  acc[m][n][r];
            }
          }
      }
      __syncthreads();
#pragma unroll
      for (int j = 0; j < 16; ++j) {
        int row = j * 8 + w;
        f32x4 d = *(const f32x4*)(smem + (row << 10) +
                                  ((lane << 4) ^ ((row & 7) << 4)));
        __builtin_nontemporal_store(
            d, (f32x4*)&Cb[(size_t)(row0 + p * 128 + row) * ldc + col0 +
                           (lane << 2)]);
      }
    }
  } else {  // EPI_SILU
    _Float16* Ch = (_Float16*)Cp + (size_t)bz * sC;
    __syncthreads();
#pragma unroll
    for (int m = 0; m < 8; ++m)
#pragma unroll
      for (int n = 0; n < 4; ++n) {
        int rl = mu * 128 + m * 16 + (kg << 2);
        int col = nu * 64 + n * 16 + fr;
#pragma unroll
        for (int r = 0; r < 4; ++r) {
          int row = rl + r;
          float v = acc[m][n][r];
          *(_Float16*)(smem + (row << 9) + ((col << 1) ^ ((row & 7) << 4))) =
              (_Float16)(v / (1.f + expf(-v)));
        }
      }
    __syncthreads();
#pragma unroll
    for (int j = 0; j < 16; ++j) {
      int row = j * 16 + w * 2 + (lane >> 5);
      int g = lane & 31;
      f16x8 d = *(const f16x8*)(smem + (row << 9) +
                                ((g << 4) ^ ((row & 7) << 4)));
      *(f16x8*)&Ch[(size_t)(row0 + row) * ldc + col0 + (g << 3)] = d;
    }
  }
#undef ST_A
#undef ST_B
#undef RD_A
#undef RD_B
#undef MFMA_Q
}

// ===========================================================================
// 128x128 m97-style GEMM (validated R1) for qk / scores / av / Wo.
// causal: 0=none, 2=av K-cap, 3=K-split (blockIdx.y = chunk idx, sKs = out
// chunk stride, K = chunk length).
// ===========================================================================
#define BM 128
#define BN 128
#define BK 32

template <int EPI>
__global__ void __launch_bounds__(256, 2) gemm_bt(
    const _Float16* __restrict__ A, long sA,
    const _Float16* __restrict__ Bt, long sB,
    void* __restrict__ Cp, long sC,
    int M, int N, int K, int lda, int ldb, int ldc, int causal,
    const _Float16* __restrict__ U, long sKs) {
  int bm = blockIdx.x, bn = blockIdx.y, bz = blockIdx.z;
  if (EPI == EPI_SCORES && bn > bm) return;
  int ks = 0;
  if (causal == 3) { ks = bn; bn = 0; }
  A += (size_t)bz * sA + (size_t)ks * K;
  Bt += (size_t)bz * sB + (size_t)ks * K;
  const size_t cbase = (size_t)bz * sC + (size_t)ks * sKs;

  int Keff = K;
  if (causal == 2) {
    int km = (bm + 1) * BM;
    Keff = km < K ? km : K;
  }

  __shared__ __align__(16) _Float16 As[BM * BK];
  __shared__ __align__(16) _Float16 Bs[BN * BK];

  int tid = threadIdx.x;
  int lane = tid & 63, wave = tid >> 6;
  int wr = (wave >> 1) << 6;
  int wc = (wave & 1) << 6;
  int row0 = bm * BM, col0 = bn * BN;
  int fr = lane & 15;
  int kg = lane >> 4;
  int srow = lane >> 2;
  int scol = (lane & 3) << 3;

  f32x4 acc[4][4];
#pragma unroll
  for (int i = 0; i < 4; i++)
#pragma unroll
    for (int j = 0; j < 4; j++)
#pragma unroll
      for (int e = 0; e < 4; e++) acc[i][j][e] = 0.f;

  const f16x8* As8 = (const f16x8*)As;
  const f16x8* Bs8 = (const f16x8*)Bs;

  for (int k0 = 0; k0 < Keff; k0 += BK) {
    __syncthreads();
#pragma unroll
    for (int i = 0; i < 2; i++) {
      int rb = (wave * 2 + i) * 16;
      load_lds16(A + (size_t)(row0 + rb + srow) * lda + k0 + scol,
                 (void*)&As[rb * BK]);
      load_lds16(Bt + (size_t)(col0 + rb + srow) * ldb + k0 + scol,
                 (void*)&Bs[rb * BK]);
    }
    asm volatile("s_waitcnt vmcnt(0)" ::: "memory");
    __syncthreads();

    f16x8 af[4], bf[4];
#pragma unroll
    for (int m = 0; m < 4; m++)
      af[m] = As8[(size_t)(wr + m * 16 + fr) * (BK / 8) + kg];
#pragma unroll
    for (int n = 0; n < 4; n++)
      bf[n] = Bs8[(size_t)(wc + n * 16 + fr) * (BK / 8) + kg];
#pragma unroll
    for (int m = 0; m < 4; m++)
#pragma unroll
      for (int n = 0; n < 4; n++)
        acc[m][n] =
            __builtin_amdgcn_mfma_f32_16x16x32_f16(af[m], bf[n], acc[m][n], 0, 0, 0);
  }

#pragma unroll
  for (int m = 0; m < 4; m++) {
    int gr0 = row0 + wr + m * 16 + (kg << 2);
#pragma unroll
    for (int n = 0; n < 4; n++) {
      int gc = col0 + wc + n * 16 + fr;
#pragma unroll
      for (int r = 0; r < 4; r++) {
        float v = acc[m][n][r];
        size_t ci = (size_t)(gr0 + r) * ldc + gc;
        if (EPI == EPI_F32) {
          ((float*)Cp + cbase)[ci] = v;
        } else if (EPI == EPI_SILU) {
          ((_Float16*)Cp + cbase)[ci] = (_Float16)(v / (1.f + expf(-v)));
        } else if (EPI == EPI_SCORES) {
          float s = v * 0.08838834764831845f;  // 1/sqrt(128)
          s = fmaxf(s, 0.f);
          s = (gc <= gr0 + r) ? s * s : 0.f;
          ((_Float16*)Cp + cbase)[ci] = (_Float16)s;
        } else if (EPI == EPI_GATED) {  // gh = u * (attn@v)
          const _Float16* Ub = U + cbase;
          ((_Float16*)Cp + cbase)[ci] = (_Float16)((float)Ub[ci] * v);
        } else {  // EPI_RESID
          ((float*)Cp)[ci] += v;
        }
      }
    }
  }
}

__global__ void __launch_bounds__(256) ln_kernel(const float* __restrict__ x,
                                                 const float* __restrict__ g,
                                                 const float* __restrict__ b,
                                                 _Float16* __restrict__ out) {
  int row = blockIdx.x, tid = threadIdx.x;
  float4 v = ((const float4*)(x + (size_t)row * Dd))[tid];
  float s = v.x + v.y + v.z + v.w;
  float q = v.x * v.x + v.y * v.y + v.z * v.z + v.w * v.w;
#pragma unroll
  for (int off = 32; off > 0; off >>= 1) {
    s += __shfl_down(s, off, 64);
    q += __shfl_down(q, off, 64);
  }
  __shared__ float ss[4], sq[4];
  int lane = tid & 63, wv = tid >> 6;
  if (lane == 0) { ss[wv] = s; sq[wv] = q; }
  __syncthreads();
  s = ss[0] + ss[1] + ss[2] + ss[3];
  q = sq[0] + sq[1] + sq[2] + sq[3];
  float mu = s * (1.f / Dd);
  float var = q * (1.f / Dd) - mu * mu;
  float rs = rsqrtf(var + 1e-5f);
  float4 gg = ((const float4*)g)[tid];
  float4 bb = ((const float4*)b)[tid];
  f16x4 o;
  o[0] = (_Float16)((v.x - mu) * rs * gg.x + bb.x);
  o[1] = (_Float16)((v.y - mu) * rs * gg.y + bb.y);
  o[2] = (_Float16)((v.z - mu) * rs * gg.z + bb.z);
  o[3] = (_Float16)((v.w - mu) * rs * gg.w + bb.w);
  ((f16x4*)(out + (size_t)row * Dd))[tid] = o;
}

__global__ void embed_kernel(const int* __restrict__ toks,
                             const float* __restrict__ emb,
                             float* __restrict__ x) {
  int row = blockIdx.x, tid = threadIdx.x;
  long t = toks[row];
  ((float4*)(x + (size_t)row * Dd))[tid] =
      ((const float4*)(emb + (size_t)t * Dd))[tid];
}

__global__ void rope_table_kernel(float* __restrict__ cosT,
                                  float* __restrict__ sinT) {
  int idx = blockIdx.x * 256 + threadIdx.x;  // T*64
  int t = idx >> 6, i = idx & 63;
  float inv = powf(10000.f, (float)(2 * i) * (-1.f / 128.f));
  float a = (float)t * inv;
  cosT[idx] = cosf(a);
  sinT[idx] = sinf(a);
}

// pre = qkpart [QKS][2][BT][Ss] f32 partial sums; reduce + rotate + f16.
__global__ void rope_kernel(const float* __restrict__ pre,
                            _Float16* __restrict__ o16,
                            const float* __restrict__ cosT,
                            const float* __restrict__ sinT) {
  int row = blockIdx.x * 4 + threadIdx.y;
  int i = threadIdx.x;
  int z = blockIdx.y;
  const size_t zs = (size_t)BT * Ss;
  const float* p = pre + (size_t)z * zs + (size_t)row * Ss;
  _Float16* o = o16 + (size_t)z * zs + (size_t)row * Ss;
  float x1 = 0.f, x2 = 0.f;
#pragma unroll
  for (int ks = 0; ks < QKS; ks++) {
    x1 += p[(size_t)ks * 2 * zs + i];
    x2 += p[(size_t)ks * 2 * zs + i + 64];
  }
  int t = row & (Tt - 1);
  float c = cosT[t * 64 + i], sn = sinT[t * 64 + i];
  o[i] = (_Float16)(x1 * c - x2 * sn);
  o[i + 64] = (_Float16)(x1 * sn + x2 * c);
}

// out(C x R) = transpose(in(R x C)), convert to f16.
template <typename TIn>
__global__ void transconv_kernel(const TIn* __restrict__ in,
                                 _Float16* __restrict__ out, int R, int C,
                                 long s_in, long s_out) {
  __shared__ float tile[64][65];
  in += (size_t)blockIdx.z * s_in;
  out += (size_t)blockIdx.z * s_out;
  int r0 = blockIdx.y * 64, c0 = blockIdx.x * 64;
  int tx = threadIdx.x & 63, ty = threadIdx.x >> 6;
#pragma unroll
  for (int p = 0; p < 16; p++) {
    int r = p * 4 + ty;
    tile[r][tx] = (float)in[(size_t)(r0 + r) * C + c0 + tx];
  }
  __syncthreads();
#pragma unroll
  for (int p = 0; p < 16; p++) {
    int r = p * 4 + ty;
    _Float16 v = (_Float16)tile[tx][r];
    _Float16* dst = &out[(size_t)(c0 + r) * R + r0 + tx];
    if (sizeof(TIn) == 4) {
      __builtin_nontemporal_store(v, dst);
    } else {
      *dst = v;
    }
  }
}

extern "C" void kernel_launch(void* const* d_in, const int* in_sizes, int n_in,
                              void* d_out, int out_size, void* d_ws,
                              size_t ws_size, hipStream_t stream) {
  const int*   tokens = (const int*)d_in[0];
  const float* emb    = (const float*)d_in[1];
  const float* Wu     = (const float*)d_in[2];
  const float* Wv     = (const float*)d_in[3];
  const float* Wq     = (const float*)d_in[4];
  const float* Wk     = (const float*)d_in[5];
  const float* Wo     = (const float*)d_in[6];
  const float* ln_g   = (const float*)d_in[7];
  const float* ln_b   = (const float*)d_in[8];
  const float* lnf_g  = (const float*)d_in[9];
  const float* lnf_b  = (const float*)d_in[10];
  const float* Wlm    = (const float*)d_in[11];
  float* out = (float*)d_out;
  (void)in_sizes; (void)n_in; (void)out_size;

  char* wsp = (char*)d_ws;
  size_t off = 0;
  auto alloc = [&](size_t bytes) -> void* {
    void* p = wsp + off;
    off = (off + bytes + 255) & ~(size_t)255;
    return p;
  };

  float*    x      = (float*)alloc((size_t)BT * Dd * 4);
  _Float16* xn     = (_Float16*)alloc((size_t)BT * Dd * 2);
  _Float16* uvh    = (_Float16*)alloc((size_t)2 * BT * Ee * 2);
  _Float16* vT     = (_Float16*)alloc((size_t)Bz * Ee * Tt * 2);
  float*    qkpart = (float*)alloc((size_t)QKS * 2 * BT * Ss * 4);
  _Float16* qkh    = (_Float16*)alloc((size_t)2 * BT * Ss * 2);
  _Float16* attn   = (_Float16*)alloc((size_t)Bz * Tt * Tt * 2);
  _Float16* gh     = (_Float16*)alloc((size_t)BT * Ee * 2);
  float*    cosT   = (float*)alloc((size_t)Tt * 64 * 4);
  float*    sinT   = (float*)alloc((size_t)Tt * 64 * 4);
  _Float16* WuvT   = (_Float16*)alloc((size_t)2 * Ll * Ee * Dd * 2);
  _Float16* WqkT   = (_Float16*)alloc((size_t)2 * Ll * Ss * Ee * 2);
  _Float16* WoT    = (_Float16*)alloc((size_t)Ll * Dd * Ee * 2);
  _Float16* WlmT   = (_Float16*)alloc((size_t)Vv * Dd * 2);
  if (off > ws_size) return;

  transconv_kernel<float><<<dim3(Ee / 64, Dd / 64, Ll), 256, 0, stream>>>(
      Wu, WuvT, Dd, Ee, (long)Dd * Ee, (long)Ee * Dd);
  transconv_kernel<float><<<dim3(Ee / 64, Dd / 64, Ll), 256, 0, stream>>>(
      Wv, WuvT + (size_t)Ll * Ee * Dd, Dd, Ee, (long)Dd * Ee, (long)Ee * Dd);
  transconv_kernel<float><<<dim3(Ss / 64, Ee / 64, Ll), 256, 0, stream>>>(
      Wq, WqkT, Ee, Ss, (long)Ee * Ss, (long)Ss * Ee);
  transconv_kernel<float><<<dim3(Ss / 64, Ee / 64, Ll), 256, 0, stream>>>(
      Wk, WqkT + (size_t)Ll * Ss * Ee, Ee, Ss, (long)Ee * Ss, (long)Ss * Ee);
  transconv_kernel<float><<<dim3(Dd / 64, Ee / 64, Ll), 256, 0, stream>>>(
      Wo, WoT, Ee, Dd, (long)Ee * Dd, (long)Dd * Ee);
  transconv_kernel<float><<<dim3(Vv / 64, Dd / 64, 1), 256, 0, stream>>>(
      Wlm, WlmT, Dd, Vv, 0, 0);

  rope_table_kernel<<<(Tt * 64) / 256, 256, 0, stream>>>(cosT, sinT);
  embed_kernel<<<BT, 256, 0, stream>>>(tokens, emb, x);

  for (int l = 0; l < Ll; l++) {
    ln_kernel<<<BT, 256, 0, stream>>>(x, ln_g + (size_t)l * Dd,
                                      ln_b + (size_t)l * Dd, xn);
    // u = silu(xn@Wu), v = silu(xn@Wv)  -- 256^2 kernel
    gemm256<EPI_SILU><<<dim3((BT / 256) * (Ee / 256), 1, 2), 512, 0, stream>>>(
        xn, 0, WuvT + (size_t)l * Ee * Dd, (long)Ll * Ee * Dd, (void*)uvh,
        (long)BT * Ee, BT, Ee, Dd, Dd, Dd, Ee);
    // q_pre/k_pre partials: K-split x4 (grid.y = chunk), chunk K = Ee/QKS
    gemm_bt<EPI_F32><<<dim3(BT / BM, QKS, 2), 256, 0, stream>>>(
        uvh, (long)BT * Ee, WqkT + (size_t)l * Ss * Ee, (long)Ll * Ss * Ee,
        (void*)qkpart, (long)BT * Ss, BT, Ss, Ee / QKS, Ee, Ee, Ss, 3, nullptr,
        (long)2 * BT * Ss);
    rope_kernel<<<dim3(BT / 4, 2), dim3(64, 4), 0, stream>>>(qkpart, qkh, cosT,
                                                             sinT);
    transconv_kernel<_Float16><<<dim3(Ee / 64, Tt / 64, Bz), 256, 0, stream>>>(
        uvh + (size_t)BT * Ee, vT, Tt, Ee, (long)Tt * Ee, (long)Ee * Tt);
    // scores = relu(mask(q@k^T * scale))^2
    gemm_bt<EPI_SCORES><<<dim3(Tt / BM, Tt / BN, Bz), 256, 0, stream>>>(
        qkh, (long)Tt * Ss, qkh + (size_t)BT * Ss, (long)Tt * Ss, (void*)attn,
        (long)Tt * Tt, Tt, Tt, Ss, Ss, Ss, Tt, 0, nullptr, 0);
    // gh = u * (attn @ v)
    gemm_bt<EPI_GATED><<<dim3(Tt / BM, Ee / BN, Bz), 256, 0, stream>>>(
        attn, (long)Tt * Tt, vT, (long)Ee * Tt, (void*)gh, (long)Tt * Ee, Tt,
        Ee, Tt, Tt, Tt, Ee, 2, uvh, 0);
    // x += gh @ Wo
    gemm_bt<EPI_RESID><<<dim3(BT / BM, Dd / BN, 1), 256, 0, stream>>>(
        gh, 0, WoT + (size_t)l * Dd * Ee, 0, (void*)x, 0, BT, Dd, Ee, Ee, Ee,
        Dd, 0, nullptr, 0);
  }

  ln_kernel<<<BT, 256, 0, stream>>>(x, lnf_g, lnf_b, xn);
  // logits = xn @ Wlm   -- 256^2 kernel
  gemm256<EPI_F32><<<dim3((BT / 256) * (Vv / 256), 1, 1), 512, 0, stream>>>(
      xn, 0, WlmT, 0, (void*)out, 0, BT, Vv, Dd, Dd, Dd, Vv);
}